// Round 1
// 152.727 us; speedup vs baseline: 1.0651x; 1.0651x over previous
//
#include <hip/hip_runtime.h>

// BurstSnn: 32-step burst-encoder + 2-layer LIF SNN, B=16384, D=187, H=50, C=5.
// One wave per batch element; 16 waves/block share one LDS weight copy.
// R9 = R8 (162us bench / 113us dispatch) + four changes:
//  (1) wave-uniform EARLY EXIT: the burst encoder is provably silent once all
//      residuals < 0.125 (every miss resets th to 0.125); worst-case last
//      encoder spike is ~t=6-7, membranes decay below threshold a few steps
//      later. Once {all r < 0.125, all mem1 <= 1, mem2 <= 1} every future
//      output is exactly 0.0f -> break and zero-fill the remaining steps.
//      Gate: SALU OR of the ballots already in SGPRs; full check only on
//      all-quiet iterations (runs ~2-3x per wave).
//  (2) v_pk_add_f32 for the float2 gather accumulates + merge chain
//      (1 VALU instead of 2; per-component adds bitwise identical, same order).
//  (3) spike count via SALU popcounts of the encoder ballots (drops per-step
//      VALU bool adds and the 6-shfl butterfly).
//  (4) 32-bit voffset store addressing (saddr form) instead of size_t math.
// L1/L2 gather structure, summation order, LDS layouts unchanged from R8.

constexpr int D = 187;
constexpr int H = 50;
constexpr int C = 5;
constexpr int T = 32;
constexpr int WPB = 16;        // waves per block
constexpr int ROWS1 = 193;     // rows rd = 33*(d>>5) + (d&31) + 1; rd=33g zero
constexpr int RS = 64;         // floats per Wt1 row (256 B)

__device__ __forceinline__ int v_ffbl(unsigned int m) {  // -1 when m == 0
    int r;
    asm("v_ffbl_b32 %0, %1" : "=v"(r) : "v"(m));
    return r;
}

// acc.x = w.x + acc.x ; acc.y = w.y + acc.y  (one VOP3P instruction)
__device__ __forceinline__ void pk_add(float2& acc, float2 w) {
    asm("v_pk_add_f32 %0, %1, %0" : "+v"(acc) : "v"(w));
}

__global__ __launch_bounds__(1024, 8)
void burst_snn_kernel(const float* __restrict__ x,
                      const float* __restrict__ W1,
                      const float* __restrict__ W2,
                      float* __restrict__ out, int B) {
    // Wt1 row layout (split-pair): floats {2l,2l+1} = {W[h=l], W[h=l+25]}, l<25.
    __shared__ float Wt1[ROWS1 * RS];   // 12352 floats = 48.25 KB
    // Wt2: 64 rows x 16 floats. row 0: zeros; rows 1..25: h=0..24;
    // row 26: zeros; rows 27..51: h=25..49; rest zeros. cols 5..15 zero pad.
    __shared__ float Wt2[1024];         // 4 KB

    const int tid = threadIdx.x;
    for (int idx = tid; idx < ROWS1 * RS; idx += 1024) {
        int rd = idx >> 6, j = idx & 63;
        int g = rd / 33;
        bool zrow = (rd == 33 * g);
        int d = rd - 1 - g;
        int l = j >> 1;
        int h = (j & 1) ? (l + 25) : l;
        float v = 0.f;
        if (!zrow && l < 25) v = W1[h * D + d];
        Wt1[idx] = v;
    }
    {
        int r = tid >> 4, c = tid & 15;   // tid covers all 1024
        int h = -1;
        if (r >= 1 && r <= 25) h = r - 1;
        else if (r >= 27 && r <= 51) h = r - 2;
        float v = 0.f;
        if (h >= 0 && c < C) v = W2[c * H + h];
        Wt2[tid] = v;
    }
    __syncthreads();

    const int lane = tid & 63;
    const int b = blockIdx.x * WPB + (tid >> 6);
    const bool active = b < B;
    const bool isLo = lane < 32;
    const int laneHalf = lane & 31;
    const int laneOff2 = laneHalf * 2;   // float2 slot within a Wt1 row

    // L1 per-group base pointers, +1 row folded in: addr(f) = base + f*64;
    // f = -1 (exhausted stream) -> zero row 33g.
    const float* gbase0 = Wt1 + ((33 * 0 + 1) << 6) + laneOff2;
    const float* gbase1 = Wt1 + ((33 * 1 + 1) << 6) + laneOff2;
    const float* gbase2 = Wt1 + ((33 * 2 + 1) << 6) + laneOff2;
    const float* gbase3 = Wt1 + ((33 * 3 + 1) << 6) + laneOff2;
    const float* gbase4 = Wt1 + ((33 * 4 + 1) << 6) + laneOff2;
    const float* gbase5 = Wt1 + ((33 * 5 + 1) << 6) + laneOff2;

    // L2 quarter-wave setup: quarter q = lane>>4 scans {lo_t,hi_t,lo_u,hi_u}.
    // base row 1 (lo) / 27 (hi); f = -1 -> row 0 / 26 (zeros).
    const int q = lane >> 4;
    const bool hiQ = (q & 1) != 0;
    const float* base2 = Wt2 + ((hiQ ? 27 : 1) << 4) + (lane & 15);

    // Encoder registers: dims lane, lane+64, lane+128 (3rd valid for lane<59)
    float r0 = 0.f, r1 = 0.f, r2 = 0.f;
    if (active) {
        const float* xb = x + (size_t)b * D;
        r0 = xb[lane];
        r1 = xb[64 + lane];
        if (lane < D - 128) r2 = xb[128 + lane];
    }
    float th0 = 0.125f, th1 = 0.125f, th2 = 0.125f;
    float mem1x = 0.f, mem1y = 0.f;  // lanes 0..24: h = lane / h = lane+25
    float mem2 = 0.f;                // lanes 0..4: c = lane
    int cnt = 0;                     // wave-uniform (SALU popcounts)

    float* outSpk = out;                     // [T][B][C]
    float* outCnt = out + (size_t)T * B * C; // [B]
    const unsigned BC = (unsigned)(B * C);
    unsigned o0 = (unsigned)(b * C + lane);  // only lanes < C store

    unsigned int ga[6], gb[6];
    int tDone = T;

    for (int t = 0; t < T; t += 2) {
        // --- two encoder steps (exact fp32 sequence), masks for t and t+1
        unsigned long long eB0, eB1, eB2, fB0, fB1, fB2;
        {
            bool s0 = r0 >= th0, s1 = r1 >= th1, s2 = r2 >= th2;
            r0 -= s0 ? th0 : 0.f; th0 = s0 ? th0 + th0 : 0.125f;
            r1 -= s1 ? th1 : 0.f; th1 = s1 ? th1 + th1 : 0.125f;
            r2 -= s2 ? th2 : 0.f; th2 = s2 ? th2 + th2 : 0.125f;
            eB0 = __ballot(s0); eB1 = __ballot(s1); eB2 = __ballot(s2);
            ga[0] = (unsigned int)eB0; ga[1] = (unsigned int)(eB0 >> 32);
            ga[2] = (unsigned int)eB1; ga[3] = (unsigned int)(eB1 >> 32);
            ga[4] = (unsigned int)eB2; ga[5] = (unsigned int)(eB2 >> 32);
        }
        {
            bool s0 = r0 >= th0, s1 = r1 >= th1, s2 = r2 >= th2;
            r0 -= s0 ? th0 : 0.f; th0 = s0 ? th0 + th0 : 0.125f;
            r1 -= s1 ? th1 : 0.f; th1 = s1 ? th1 + th1 : 0.125f;
            r2 -= s2 ? th2 : 0.f; th2 = s2 ? th2 + th2 : 0.125f;
            fB0 = __ballot(s0); fB1 = __ballot(s1); fB2 = __ballot(s2);
            gb[0] = (unsigned int)fB0; gb[1] = (unsigned int)(fB0 >> 32);
            gb[2] = (unsigned int)fB1; gb[3] = (unsigned int)(fB1 >> 32);
            gb[4] = (unsigned int)fB2; gb[5] = (unsigned int)(fB2 >> 32);
        }
        // spike count: uniform SALU popcounts of the ballots
        cnt += __popcll(eB0) + __popcll(eB1) + __popcll(eB2)
             + __popcll(fB0) + __popcll(fB1) + __popcll(fB2);

        // Per-lane masks: lanes<32 step t, lanes>=32 step t+1
        unsigned int vm0 = isLo ? ga[0] : gb[0];
        unsigned int vm1 = isLo ? ga[1] : gb[1];
        unsigned int vm2 = isLo ? ga[2] : gb[2];
        unsigned int vm3 = isLo ? ga[3] : gb[3];
        unsigned int vm4 = isLo ? ga[4] : gb[4];
        unsigned int vm5 = isLo ? ga[5] : gb[5];

        float2 a0 = {0.f, 0.f}, a1 = {0.f, 0.f}, a2 = {0.f, 0.f};
        float2 a3 = {0.f, 0.f}, a4 = {0.f, 0.f}, a5 = {0.f, 0.f};

        // --- phase 0: streams over groups {0,2,4}
        {
            int n0 = __popc(ga[0]) > __popc(gb[0]) ? __popc(ga[0]) : __popc(gb[0]);
            int n2g = __popc(ga[2]) > __popc(gb[2]) ? __popc(ga[2]) : __popc(gb[2]);
            int n4 = __popc(ga[4]) > __popc(gb[4]) ? __popc(ga[4]) : __popc(gb[4]);
            int n = n0 > n2g ? n0 : n2g;
            n = n > n4 ? n : n4;
            for (; n > 0; --n) {
                int f0 = v_ffbl(vm0); vm0 &= vm0 - 1;
                int f2 = v_ffbl(vm2); vm2 &= vm2 - 1;
                int f4 = v_ffbl(vm4); vm4 &= vm4 - 1;
                float2 w0 = *(const float2*)(gbase0 + f0 * 64);
                float2 w2 = *(const float2*)(gbase2 + f2 * 64);
                float2 w4 = *(const float2*)(gbase4 + f4 * 64);
                pk_add(a0, w0);
                pk_add(a2, w2);
                pk_add(a4, w4);
            }
        }
        // --- phase 1: streams over groups {1,3,5}
        {
            int n1 = __popc(ga[1]) > __popc(gb[1]) ? __popc(ga[1]) : __popc(gb[1]);
            int n3 = __popc(ga[3]) > __popc(gb[3]) ? __popc(ga[3]) : __popc(gb[3]);
            int n5 = __popc(ga[5]) > __popc(gb[5]) ? __popc(ga[5]) : __popc(gb[5]);
            int n = n1 > n3 ? n1 : n3;
            n = n > n5 ? n : n5;
            for (; n > 0; --n) {
                int f1 = v_ffbl(vm1); vm1 &= vm1 - 1;
                int f3 = v_ffbl(vm3); vm3 &= vm3 - 1;
                int f5 = v_ffbl(vm5); vm5 &= vm5 - 1;
                float2 w1 = *(const float2*)(gbase1 + f1 * 64);
                float2 w3 = *(const float2*)(gbase3 + f3 * 64);
                float2 w5 = *(const float2*)(gbase5 + f5 * 64);
                pk_add(a1, w1);
                pk_add(a3, w3);
                pk_add(a5, w5);
            }
        }

        // Merge partials in ascending-d block order (packed; order identical)
        float2 cm = a0;
        pk_add(cm, a1); pk_add(cm, a2); pk_add(cm, a3);
        pk_add(cm, a4); pk_add(cm, a5);
        float c1x = cm.x, c1y = cm.y;                  // step t   (lanes 0..24)
        float c2x = __shfl_down(cm.x, 32);             // step t+1 -> lanes 0..24
        float c2y = __shfl_down(cm.y, 32);

        // --- LIF layer 1, step t
        mem1x = 0.9f * mem1x + c1x;
        bool spx = (mem1x - 1.0f > 0.f) && (lane < 25);
        mem1x -= spx ? 1.0f : 0.f;
        mem1y = 0.9f * mem1y + c1y;
        bool spy = (mem1y - 1.0f > 0.f) && (lane < 25);
        mem1y -= spy ? 1.0f : 0.f;
        unsigned int lo_t = (unsigned int)(__ballot(spx) & 0x1FFFFFFull); // h<25
        unsigned int hi_t = (unsigned int)(__ballot(spy) & 0x1FFFFFFull); // h>=25
        // --- LIF layer 1, step t+1
        mem1x = 0.9f * mem1x + c2x;
        bool qx = (mem1x - 1.0f > 0.f) && (lane < 25);
        mem1x -= qx ? 1.0f : 0.f;
        mem1y = 0.9f * mem1y + c2y;
        bool qy = (mem1y - 1.0f > 0.f) && (lane < 25);
        mem1y -= qy ? 1.0f : 0.f;
        unsigned int lo_u = (unsigned int)(__ballot(qx) & 0x1FFFFFFull);
        unsigned int hi_u = (unsigned int)(__ballot(qy) & 0x1FFFFFFull);

        // --- layer-2 quarter-wave gather: q0..q3 scan {lo_t,hi_t,lo_u,hi_u};
        //     one ds_read_b32 per trip covers 4 spikes; f=-1 -> zero row.
        int p0 = __popc(lo_t), p1 = __popc(hi_t), p2 = __popc(lo_u), p3 = __popc(hi_u);
        int n2 = p0 > p1 ? p0 : p1;
        n2 = n2 > p2 ? n2 : p2;
        n2 = n2 > p3 ? n2 : p3;
        float cq = 0.f;
        if (n2) {
            unsigned int vmq = isLo ? (hiQ ? hi_t : lo_t) : (hiQ ? hi_u : lo_u);
            for (; n2 > 0; --n2) {
                int f = v_ffbl(vmq); vmq &= vmq - 1;
                cq += *(base2 + f * 16);
            }
        }
        // combine quarters: lanes 0..4 get (lo+hi) for t; +32 lanes for t+1
        float tmp = cq + __shfl_down(cq, 16);
        float cur2 = tmp;                              // step t   (lanes 0..4)
        float c2t1 = __shfl_down(tmp, 32);             // step t+1 -> lanes 0..4

        // --- LIF layer 2, step t
        mem2 = 0.9f * mem2 + cur2;
        bool sp2 = (mem2 - 1.0f > 0.f);
        mem2 -= sp2 ? 1.0f : 0.f;
        if (active && lane < C) outSpk[o0] = sp2 ? 1.0f : 0.0f;
        // --- LIF layer 2, step t+1
        mem2 = 0.9f * mem2 + c2t1;
        bool sp2b = (mem2 - 1.0f > 0.f);
        mem2 -= sp2b ? 1.0f : 0.f;
        if (active && lane < C) outSpk[o0 + BC] = sp2b ? 1.0f : 0.0f;
        o0 += 2u * BC;

        // --- early exit: cheap SALU quiet gate, then exact dead check.
        // Dead state: all r < 0.125 (encoder permanently silent: th >= 0.125
        // always), all mem1 <= 1 and mem2 <= 1 (0.9*mem can never recross 1).
        // Then every future output is exactly 0.0f.
        unsigned encAny = ga[0] | ga[1] | ga[2] | ga[3] | ga[4] | ga[5]
                        | gb[0] | gb[1] | gb[2] | gb[3] | gb[4] | gb[5];
        unsigned l1Any = lo_t | hi_t | lo_u | hi_u;
        if ((encAny | l1Any) == 0u) {
            float rmax = fmaxf(fmaxf(r0, r1), r2);      // residuals are >= 0
            unsigned long long am = __ballot(rmax >= 0.125f);
            unsigned long long m1 =
                __ballot(fmaxf(mem1x, mem1y) > 1.0f) & 0x1FFFFFFull;
            unsigned long long m2 = __ballot(mem2 > 1.0f) & 0x1Full;
            if ((am | m1 | m2) == 0ull) { tDone = t + 2; break; }
        }
    }

    // --- zero-fill the provably-silent tail steps
    if (active && lane < C) {
        for (int tt = tDone; tt < T; ++tt) {
            outSpk[o0] = 0.0f;
            o0 += BC;
        }
    }
    // --- spike count (wave-uniform), write counts[b]
    if (active && lane == 0) outCnt[b] = (float)cnt;
}

extern "C" void kernel_launch(void* const* d_in, const int* in_sizes, int n_in,
                              void* d_out, int out_size, void* d_ws, size_t ws_size,
                              hipStream_t stream) {
    const float* x  = (const float*)d_in[0];
    const float* W1 = (const float*)d_in[1];
    const float* W2 = (const float*)d_in[2];
    float* out = (float*)d_out;
    const int B = in_sizes[0] / D;
    const int blocks = (B + WPB - 1) / WPB;
    burst_snn_kernel<<<blocks, 1024, 0, stream>>>(x, W1, W2, out, B);
}